// Round 8
// baseline (236.501 us; speedup 1.0000x reference)
//
#include <hip/hip_runtime.h>

// ---------------------------------------------------------------------------
// MultiAttention: x[T=1024,N=8,D=1024] -> QKV proj -> 16-head causal attention
// with key padding -> out proj. bf16 MFMA compute, f32 accumulation.
// Round 8: GEMMs rewritten as 256-tile 8-wave ring-pipelined kernel:
// 3-slot LDS ring (BK=32), counted vmcnt(8) (never drains), XOR-swizzled LDS
// (4-way max), XCD-bijective block swizzle, setprio around MFMA cluster.
// ---------------------------------------------------------------------------

#define T_SEQ 1024
#define NB 8
#define DMODEL 1024
#define NHEADS 16
#define DK 64

typedef __attribute__((ext_vector_type(8))) short bf16x8;
typedef __attribute__((ext_vector_type(8))) unsigned short u16x8;
typedef __attribute__((ext_vector_type(4))) float f32x4;

#define MFMA16(a, b, c) __builtin_amdgcn_mfma_f32_16x16x32_bf16((a), (b), (c), 0, 0, 0)
#define WAITVM(N) asm volatile("s_waitcnt vmcnt(" #N ")" ::: "memory")

__device__ __forceinline__ unsigned short f2bf(float f) {
  unsigned int u = __float_as_uint(f);
  unsigned int r = (u + 0x7FFFu + ((u >> 16) & 1u)) >> 16;  // RNE
  return (unsigned short)r;
}

__device__ __forceinline__ void gload16(const void* g, void* l) {
  __builtin_amdgcn_global_load_lds((const __attribute__((address_space(1))) void*)g,
                                   (__attribute__((address_space(3))) void*)l, 16, 0, 0);
}

// ---------------- fused f32 -> bf16 conversion (x, w_in, w_o) --------------
#define XQ (T_SEQ * NB * DMODEL / 4)
#define WIQ (3 * DMODEL * DMODEL / 4)
#define WOQ (DMODEL * DMODEL / 4)

__global__ __launch_bounds__(256) void cvt_all(const float* __restrict__ x,
                                               const float* __restrict__ w_in,
                                               const float* __restrict__ w_o,
                                               unsigned short* __restrict__ xb,
                                               unsigned short* __restrict__ wib,
                                               unsigned short* __restrict__ wob) {
  int i = blockIdx.x * blockDim.x + threadIdx.x;
  const float* src;
  unsigned short* dst;
  int j;
  if (i < XQ) {
    src = x; dst = xb; j = i;
  } else if (i < XQ + WIQ) {
    src = w_in; dst = wib; j = i - XQ;
  } else if (i < XQ + WIQ + WOQ) {
    src = w_o; dst = wob; j = i - XQ - WIQ;
  } else {
    return;
  }
  float4 v = reinterpret_cast<const float4*>(src)[j];
  uint2 o;
  o.x = (unsigned)f2bf(v.x) | ((unsigned)f2bf(v.y) << 16);
  o.y = (unsigned)f2bf(v.z) | ((unsigned)f2bf(v.w) << 16);
  reinterpret_cast<uint2*>(dst)[j] = o;
}

// ---------------- per-batch valid length from key_padding_mask -------------
__global__ void len_kernel(const void* __restrict__ kpm_raw, int* __restrict__ lens) {
  const int* ki = (const int*)kpm_raw;
  const unsigned char* kb = (const unsigned char*)kpm_raw;
  const int lane = threadIdx.x;  // 1 block, 64 threads
  int bad = 0;
  for (int i = lane; i < 2048; i += 64) {
    unsigned v = (unsigned)ki[i];
    bad |= (v != 0u && v != 1u && v != 0x3F800000u) ? 1 : 0;
  }
  bad = __any(bad);  // 1 -> byte elements, 0 -> 4-byte elements
  for (int n = 0; n < NB; ++n) {
    int cnt = 0;
    if (bad) {
      for (int s = lane; s < T_SEQ; s += 64) cnt += (kb[n * T_SEQ + s] == 0) ? 1 : 0;
    } else {
      for (int s = lane; s < T_SEQ; s += 64) cnt += (ki[n * T_SEQ + s] == 0) ? 1 : 0;
    }
    for (int m = 1; m < 64; m <<= 1) cnt += __shfl_xor(cnt, m);
    if (lane == 0) lens[n] = cnt;
  }
}

// ---------------- 256x(BN) bf16 GEMM, C = A * B^T + bias -------------------
// 512 threads = 8 waves (2 M x 4 N); per-wave output 128 x (BN/4).
// BK=32; LDS: 3-slot ring per operand; XOR swizzle k^=16 when row&8.
// Pipeline: stage tile t+2 || compute tile t; vmcnt(8) keeps >=2 tiles in
// flight (no drain in steady state); 2 barriers per K-tile.
// EPI==0: QKV scatter epilogue ([n,h,t,dk] for q,k,v). EPI==1: f32 C.
template <int EPI, int BN>
__global__ __launch_bounds__(512, 2) void gemm256_kernel(
    const unsigned short* __restrict__ A, const unsigned short* __restrict__ B,
    const float* __restrict__ bias, float* __restrict__ Cf,
    unsigned short* __restrict__ qb, unsigned short* __restrict__ kb,
    unsigned short* __restrict__ vb, int M, int N, int K, int NBN) {
  constexpr int NF = BN / 64;           // N-frags per wave (4 or 2)
  constexpr int BCH = BN * 32 / 8;      // B chunks per tile (1024 or 512)
  __shared__ unsigned short a_lds[3 * 256 * 32];
  __shared__ unsigned short b_lds[3 * BN * 32];

  // bijective XCD swizzle, row-major block enumeration (bm*NBN + bn):
  // XCD x gets a contiguous band of bm rows -> A panel ~2MB L2-resident.
  const int cpx = gridDim.x >> 3;  // grid divisible by 8 by construction
  const int lid = (blockIdx.x & 7) * cpx + (blockIdx.x >> 3);
  const int bm = lid / NBN, bn = lid % NBN;
  const int brow = bm * 256, bcol = bn * BN;

  const int tid = threadIdx.x;
  const int w = tid >> 6, lane = tid & 63;
  const int l15 = lane & 15, lg = lane >> 4;
  const int wm = w >> 2, wn = w & 3;  // 2x4 wave grid

  const unsigned short* Abase = A + (size_t)brow * K;
  const unsigned short* Bbase = B + (size_t)bcol * K;

  f32x4 acc[8][NF] = {};

  const int KT = K >> 5;  // K-tiles of 32

  // ---- staging helper (inlined twice below via lambda) ----
  auto stage_tile = [&](int t, int slot) {
    const int k0 = t << 5;
    unsigned short* da = a_lds + slot * (256 * 32);
    unsigned short* db = b_lds + slot * (BN * 32);
#pragma unroll
    for (int j = 0; j < 2; ++j) {
      const int c = tid + 512 * j;  // 1024 A-chunks of 16B
      const int r = c >> 2, s2 = c & 3;
      const int s2p = s2 ^ (((r >> 3) & 1) << 1);  // inverse swizzle on source
      gload16(Abase + (size_t)r * K + k0 + s2p * 8, da + c * 8);
    }
#pragma unroll
    for (int j = 0; j < BCH / 512; ++j) {
      const int c = tid + 512 * j;
      const int r = c >> 2, s2 = c & 3;
      const int s2p = s2 ^ (((r >> 3) & 1) << 1);
      gload16(Bbase + (size_t)r * K + k0 + s2p * 8, db + c * 8);
    }
  };

  // prologue: tiles 0,1 into slots 0,1
  stage_tile(0, 0);
  stage_tile(1, 1);

  int sl = 0, ss = 2;
  for (int t = 0; t < KT; ++t) {
    if (t + 2 < KT) stage_tile(t + 2, ss);
    // counted waits: per-tile loads/thread = 4 (BN=256) or 3 (BN=128)
    if (t + 2 < KT) {
      if constexpr (BN == 256) WAITVM(8); else WAITVM(6);
    } else if (t + 1 < KT) {
      if constexpr (BN == 256) WAITVM(4); else WAITVM(3);
    } else {
      WAITVM(0);
    }
    __builtin_amdgcn_s_barrier();  // tile t resident in slot sl

    const unsigned short* as = a_lds + sl * (256 * 32);
    const unsigned short* bs = b_lds + sl * (BN * 32);
    bf16x8 bf[NF];
#pragma unroll
    for (int nc = 0; nc < NF; ++nc) {
      const int rl = wn * (BN / 4) + nc * 16 + l15;
      bf[nc] = *reinterpret_cast<const bf16x8*>(&bs[rl * 32 + (lg * 8 ^ ((rl & 8) << 1))]);
    }
    __builtin_amdgcn_s_setprio(1);
#pragma unroll
    for (int mf = 0; mf < 8; ++mf) {
      const int rl = wm * 128 + mf * 16 + l15;
      const bf16x8 af =
          *reinterpret_cast<const bf16x8*>(&as[rl * 32 + (lg * 8 ^ ((rl & 8) << 1))]);
#pragma unroll
      for (int nc = 0; nc < NF; ++nc) acc[mf][nc] = MFMA16(af, bf[nc], acc[mf][nc]);
    }
    __builtin_amdgcn_s_setprio(0);
    __builtin_amdgcn_s_barrier();  // all waves done reading slot sl
    sl = sl == 2 ? 0 : sl + 1;
    ss = ss == 2 ? 0 : ss + 1;
  }

  // ---- epilogue ----
#pragma unroll
  for (int nc = 0; nc < NF; ++nc) {
    const int col = bcol + wn * (BN / 4) + nc * 16 + l15;
    const float bv = bias[col];
    unsigned short* basep = nullptr;
    if (EPI == 0) basep = col < DMODEL ? qb : (col < 2 * DMODEL ? kb : vb);
    const int c2 = col & (DMODEL - 1);
    const int hh = c2 >> 6, dk = c2 & 63;
#pragma unroll
    for (int mf = 0; mf < 8; ++mf) {
#pragma unroll
      for (int r = 0; r < 4; ++r) {
        const int row = brow + wm * 128 + mf * 16 + lg * 4 + r;  // C/D rows
        const float v = acc[mf][nc][r] + bv;
        if (EPI == 1) {
          Cf[(size_t)row * N + col] = v;
        } else {
          const int t = row >> 3, n = row & 7;  // row = t*NB + n
          basep[(size_t)(n * NHEADS + hh) * (T_SEQ * DK) + t * DK + dk] = f2bf(v);
        }
      }
    }
  }
}

// ---------------- V transpose: [n,h,t,dk] -> [n,h,dk,t] --------------------
__global__ __launch_bounds__(256) void v_transpose(const unsigned short* __restrict__ vin,
                                                   unsigned short* __restrict__ vout) {
  __shared__ unsigned short tl[64 * 72];  // +8 pad breaks bank patterns
  const int b = blockIdx.x;
  const int nh = b >> 4, tt = b & 15;
  const unsigned short* src = vin + (size_t)nh * (T_SEQ * DK) + (size_t)tt * 64 * DK;
  unsigned short* dst = vout + (size_t)nh * (T_SEQ * DK) + tt * 64;
  const int tid = threadIdx.x;
#pragma unroll
  for (int i = 0; i < 2; ++i) {
    const int c = i * 256 + tid;         // 512 chunks
    const int t = c >> 3, d0 = (c & 7) * 8;
    *reinterpret_cast<u16x8*>(&tl[t * 72 + d0]) =
        *reinterpret_cast<const u16x8*>(src + t * DK + d0);
  }
  __syncthreads();
#pragma unroll
  for (int i = 0; i < 2; ++i) {
    const int c = i * 256 + tid;
    const int dk = c & 63, t0 = (c >> 6) * 8;
    u16x8 o;
#pragma unroll
    for (int j = 0; j < 8; ++j) o[j] = tl[(t0 + j) * 72 + dk];
    *reinterpret_cast<u16x8*>(dst + (size_t)dk * T_SEQ + t0) = o;
  }
}

// ---------------- fused causal attention, online softmax ------------------
#define PLD 72  // 144B row stride for the P slab

__device__ __forceinline__ void stage_kv(const unsigned short* kp_base,
                                         const unsigned short* vp_base, int s0,
                                         unsigned short* kl, unsigned short* vl, int tid) {
#pragma unroll
  for (int i = 0; i < 2; ++i) {
    const int seg = i * 256 + tid;            // 512 chunks of 16B each
    const int r = seg >> 3, c8 = seg & 7;     // row, stored chunk slot
    const int xc = (c8 ^ (r & 7)) * 8;        // logical chunk for this slot
    gload16(kp_base + (((size_t)(s0 + r)) << 6) + xc, kl + seg * 8);
    gload16(vp_base + (size_t)r * T_SEQ + s0 + xc, vl + seg * 8);
  }
}

__global__ __launch_bounds__(256, 4) void attn_kernel(
    const unsigned short* __restrict__ qb, const unsigned short* __restrict__ kb,
    const unsigned short* __restrict__ vtb, const int* __restrict__ lens,
    unsigned short* __restrict__ attn_out) {
  __shared__ unsigned short k_lds[2][64 * 64];  // 8KB x2
  __shared__ unsigned short v_lds[2][64 * 64];  // 8KB x2
  __shared__ unsigned short p_lds[4 * 16 * PLD];
  const int bid = blockIdx.x;
  const int x = bid & 7;              // hw XCD (round-robin dispatch)
  const int rem = bid >> 3;
  const int nh = (rem & 15) * 8 + x;  // (n*H + h): 16 heads per XCD
  const int pr = rem >> 4;            // pair index 0..7
  const int n = nh >> 4;
  const int h = nh & 15;
  const int tid = threadIdx.x;
  const int w = tid >> 6, lane = tid & 63;
  const int l15 = lane & 15, lg = lane >> 4;
  const int len_n = lens[n];
  const int ltiles = (len_n + 63) >> 6;  // padding bound

  const unsigned short* kp_base = kb + (size_t)nh * (T_SEQ * DK);
  const unsigned short* vp_base = vtb + (size_t)nh * (T_SEQ * DK);
  const unsigned short* q_base = qb + (size_t)nh * (T_SEQ * DK);
  unsigned short* pw = p_lds + w * 16 * PLD;

  bf16x8 ones;
#pragma unroll
  for (int j = 0; j < 8; ++j) ones[j] = (short)0x3F80;  // bf16 1.0

  int cur = 0;
#pragma unroll
  for (int p = 0; p < 2; ++p) {
    const int qt = p == 0 ? pr : 15 - pr;  // q-tile index
    const int q0 = qt * 64;

    const unsigned short* qp = q_base + (size_t)(q0 + w * 16 + l15) * DK;
    const bf16x8 qa0 = *reinterpret_cast<const bf16x8*>(qp + lg * 8);
    const bf16x8 qa1 = *reinterpret_cast<const bf16x8*>(qp + 32 + lg * 8);

    f32x4 o_acc[4] = {};
    float m_r[4], l_r[4];
#pragma unroll
    for (int r = 0; r < 4; ++r) { m_r[r] = -1e30f; l_r[r] = 0.f; }

    const int t_base = q0 + w * 16 + lg * 4;  // C/D layout row base
    int ntiles = qt + 1;                      // causal bound (block-uniform)
    if (ltiles < ntiles) ntiles = ltiles;

    stage_kv(kp_base, vp_base, 0, k_lds[cur], v_lds[cur], tid);

    for (int tile = 0; tile < ntiles; ++tile) {
      const int s0 = tile * 64;
      if (tile + 1 < ntiles) {
        stage_kv(kp_base, vp_base, s0 + 64, k_lds[cur ^ 1], v_lds[cur ^ 1], tid);
        WAITVM(4);
      } else {
        WAITVM(0);
      }
      __builtin_amdgcn_s_barrier();  // buf[cur] visible to all waves

      f32x4 s_acc[4] = {};
#pragma unroll
      for (int ct = 0; ct < 4; ++ct) {
        const int rl = ct * 16 + l15;
        const int c0 = lg ^ (rl & 7);
        const bf16x8 kf0 = *reinterpret_cast<const bf16x8*>(&k_lds[cur][rl * 64 + c0 * 8]);
        const bf16x8 kf1 = *reinterpret_cast<const bf16x8*>(&k_lds[cur][rl * 64 + (c0 ^ 4) * 8]);
        s_acc[ct] = MFMA16(qa0, kf0, s_acc[ct]);
        s_acc[ct] = MFMA16(qa1, kf1, s_acc[ct]);
      }
      bf16x8 vb[4][2];
#pragma unroll
      for (int ct = 0; ct < 4; ++ct) {
        const int rl = ct * 16 + l15;
        const int c0 = lg ^ (rl & 7);
        vb[ct][0] = *reinterpret_cast<const bf16x8*>(&v_lds[cur][rl * 64 + c0 * 8]);
        vb[ct][1] = *reinterpret_cast<const bf16x8*>(&v_lds[cur][rl * 64 + (c0 ^ 4) * 8]);
      }
      float sv[4][4];
      const bool need_mask = (tile == qt) | (((tile + 1) << 6) > len_n);
      if (need_mask) {
#pragma unroll
        for (int ct = 0; ct < 4; ++ct) {
          const int s = s0 + ct * 16 + l15;
#pragma unroll
          for (int r = 0; r < 4; ++r) {
            const int t = t_base + r;
            const float v = s_acc[ct][r] * 0.125f;  // 1/sqrt(64)
            sv[ct][r] = (s > t || s >= len_n) ? -1e30f : v;
          }
        }
      } else {
#pragma unroll
        for (int ct = 0; ct < 4; ++ct)
#pragma unroll
          for (int r = 0; r < 4; ++r) sv[ct][r] = s_acc[ct][r] * 0.125f;
      }
      float sc_r[4];
#pragma unroll
      for (int r = 0; r < 4; ++r) {
        float mx = fmaxf(fmaxf(sv[0][r], sv[1][r]), fmaxf(sv[2][r], sv[3][r]));
        mx = fmaxf(mx, __shfl_xor(mx, 1));
        mx = fmaxf(mx, __shfl_xor(mx, 2));
        mx = fmaxf(mx, __shfl_xor(mx, 4));
        mx = fmaxf(mx, __shfl_xor(mx, 8));
        const float mnew = fmaxf(m_r[r], mx);
        sc_r[r] = __expf(m_r[r] - mnew);
        m_r[r] = mnew;
#pragma unroll
        for (int ct = 0; ct < 4; ++ct) {
          const float pp = __expf(sv[ct][r] - mnew);
          pw[(lg * 4 + r) * PLD + ct * 16 + l15] = f2bf(pp);
        }
#pragma unroll
        for (int ct = 0; ct < 4; ++ct) o_acc[ct][r] *= sc_r[r];
      }
      const bf16x8 pa0 = *reinterpret_cast<const bf16x8*>(pw + l15 * PLD + lg * 8);
      const bf16x8 pa1 = *reinterpret_cast<const bf16x8*>(pw + l15 * PLD + 32 + lg * 8);
      f32x4 lacc = {};
      lacc = MFMA16(pa0, ones, lacc);  // row-sums of P; rows match o_acc layout
      lacc = MFMA16(pa1, ones, lacc);
#pragma unroll
      for (int ct = 0; ct < 4; ++ct) {
        o_acc[ct] = MFMA16(pa0, vb[ct][0], o_acc[ct]);
        o_acc[ct] = MFMA16(pa1, vb[ct][1], o_acc[ct]);
      }
#pragma unroll
      for (int r = 0; r < 4; ++r) l_r[r] = l_r[r] * sc_r[r] + lacc[r];

      __builtin_amdgcn_s_barrier();  // all waves done reading buf[cur]
      cur ^= 1;
    }

    float inv_l[4];
#pragma unroll
    for (int r = 0; r < 4; ++r) inv_l[r] = 1.0f / l_r[r];
#pragma unroll
    for (int ct = 0; ct < 4; ++ct) {
      const int d = h * DK + ct * 16 + l15;
#pragma unroll
      for (int r = 0; r < 4; ++r) {
        const int t = t_base + r;
        attn_out[((size_t)t * NB + n) * DMODEL + d] = f2bf(o_acc[ct][r] * inv_l[r]);
      }
    }
  }
}

// ---------------------------------------------------------------------------
extern "C" void kernel_launch(void* const* d_in, const int* in_sizes, int n_in,
                              void* d_out, int out_size, void* d_ws, size_t ws_size,
                              hipStream_t stream) {
  const float* x = (const float*)d_in[0];
  const float* w_in = (const float*)d_in[1];
  const float* b_in = (const float*)d_in[2];
  const float* w_o = (const float*)d_in[3];
  const float* b_o = (const float*)d_in[4];
  // d_in[5] attn_mask: causal triu(k=1) -- computed analytically in-kernel
  const void* kpm = (const void*)d_in[6];
  float* out = (float*)d_out;

  char* ws = (char*)d_ws;
  unsigned short* x_bf = (unsigned short*)(ws + 0);           // 16.78 MB
  unsigned short* win_bf = (unsigned short*)(ws + 16777216);  // 6.29 MB
  unsigned short* wo_bf = (unsigned short*)(ws + 23068672);   // 2.10 MB
  unsigned short* qb = (unsigned short*)(ws + 25165824);      // 16.78 MB
  unsigned short* kb = (unsigned short*)(ws + 41943040);      // 16.78 MB
  unsigned short* vb = (unsigned short*)(ws + 58720256);      // 16.78 MB  [n,h,t,dk]
  unsigned short* vtb = (unsigned short*)(ws + 75497472);     // 16.78 MB  [n,h,dk,t]
  unsigned short* attn_bf = (unsigned short*)(ws + 0);        // alias x_bf
  int* lens = (int*)(ws + 92274688);                          // 32 B

  cvt_all<<<(XQ + WIQ + WOQ + 255) / 256, 256, 0, stream>>>(x, w_in, w_o, x_bf, win_bf, wo_bf);
  len_kernel<<<1, 64, 0, stream>>>(kpm, lens);

  // QKV projection: [8192,1024] x [3072,1024]^T; grid 32x12=384 (div by 8)
  gemm256_kernel<0, 256><<<384, 512, 0, stream>>>(x_bf, win_bf, b_in, nullptr, qb, kb, vb,
                                                  T_SEQ * NB, 3 * DMODEL, DMODEL, 12);
  // V transpose for attention PV operand
  v_transpose<<<NB * NHEADS * 16, 256, 0, stream>>>(vb, vtb);
  // fused attention (paired q-tiles, XCD-local heads, LDS-pipelined K/V)
  attn_kernel<<<NB * NHEADS * 8, 256, 0, stream>>>(qb, kb, vtb, lens, attn_bf);
  // output projection: [8192,1024] x [1024,1024]^T -> f32; grid 32x8=256
  gemm256_kernel<1, 128><<<256, 512, 0, stream>>>(attn_bf, wo_bf, b_o, out, nullptr, nullptr,
                                                  nullptr, T_SEQ * NB, DMODEL, DMODEL, 8);
}